// Round 3
// baseline (981.687 us; speedup 1.0000x reference)
//
#include <hip/hip_runtime.h>

// SAGAN self-attention, B=4, C=512, Cp=64, N=64*64=4096.
// Input/output dtype (fp32 vs bf16) detected at runtime from the data:
// fp32 words misread as bf16 pairs give implausible low-halves (~46% |v|>1e3,
// ~1/256 NaN); true bf16 N(0,1) data gives none. Prior rounds' NaN output is
// consistent with fp32 inputs misread as bf16.
// Intermediates (fx/gx/hx/op) stored bf16 in ws; two-pass online softmax.

#define NB 4
#define CC 512
#define CP 64
#define NN 4096

__device__ __forceinline__ float bf2f_u(unsigned short h) {
    return __uint_as_float((unsigned)h << 16);
}
__device__ __forceinline__ float bf16lo(unsigned v) { return __uint_as_float(v << 16); }
__device__ __forceinline__ float bf16hi(unsigned v) { return __uint_as_float(v & 0xffff0000u); }
__device__ __forceinline__ unsigned short f2bf(float f) {
    unsigned u = __float_as_uint(f);
    u += 0x7fffu + ((u >> 16) & 1u);   // RNE
    return (unsigned short)(u >> 16);
}
__device__ __forceinline__ unsigned pack2bf(float a, float b) {
    return (unsigned)f2bf(a) | ((unsigned)f2bf(b) << 16);
}
__device__ __forceinline__ float4 ld4bf(const unsigned short* p) {
    uint2 v = *reinterpret_cast<const uint2*>(p);
    return make_float4(bf16lo(v.x), bf16hi(v.x), bf16lo(v.y), bf16hi(v.y));
}
__device__ __forceinline__ void st4bf(unsigned short* p, float a, float b, float c, float d) {
    uint2 o; o.x = pack2bf(a, b); o.y = pack2bf(c, d);
    *reinterpret_cast<uint2*>(p) = o;
}
__device__ __forceinline__ float ldS(const void* p, long i, int f32) {
    return f32 ? ((const float*)p)[i] : bf2f_u(((const unsigned short*)p)[i]);
}
__device__ __forceinline__ float2 ld2(const void* p, long i, int f32) {
    if (f32) return *reinterpret_cast<const float2*>((const float*)p + i);
    unsigned v = *reinterpret_cast<const unsigned*>((const unsigned short*)p + i);
    return make_float2(bf16lo(v), bf16hi(v));
}
__device__ __forceinline__ float4 ld4(const void* p, long i, int f32) {
    if (f32) return *reinterpret_cast<const float4*>((const float*)p + i);
    return ld4bf((const unsigned short*)p + i);
}

// ---------------------------------------------------------------------------
// dtype detector: writes 1 if fp32, 0 if bf16.
// ---------------------------------------------------------------------------
__global__ __launch_bounds__(256) void detect_kernel(
    const unsigned* __restrict__ x, int* __restrict__ flag)
{
    __shared__ int red[256];
    const int t = threadIdx.x;
    int bad = 0;
    for (int i = t; i < 4096; i += 256) {
        unsigned w = x[i];
        float f0 = __uint_as_float(w << 16);
        float f1 = __uint_as_float(w & 0xffff0000u);
        float a0 = fabsf(f0), a1 = fabsf(f1);
        if (!(a0 <= 1e3f) || (f0 != 0.f && a0 < 1e-20f)) bad++;
        if (!(a1 <= 1e3f) || (f1 != 0.f && a1 < 1e-20f)) bad++;
    }
    red[t] = bad;
    __syncthreads();
    for (int s = 128; s > 0; s >>= 1) { if (t < s) red[t] += red[t + s]; __syncthreads(); }
    if (t == 0) *flag = (red[0] > 64) ? 1 : 0;
}

// ---------------------------------------------------------------------------
// sigma: v = normalize(W^T u); sigma = u^T (W v); writes 1/sigma.
// ---------------------------------------------------------------------------
__global__ __launch_bounds__(512) void sigma_kernel(
    const void* __restrict__ Wf, const void* __restrict__ Wg,
    const void* __restrict__ Wh, const void* __restrict__ Wv,
    const void* __restrict__ uf, const void* __restrict__ ug,
    const void* __restrict__ uh, const void* __restrict__ uv,
    const int* __restrict__ dflag, float* __restrict__ sig)
{
    const int f32 = *dflag;
    const int w = blockIdx.x;
    const void* W;
    const void* u;
    int R, Cc, sh;
    if (w == 0)      { W = Wf; u = uf; R = 64;  Cc = 512; sh = 9; }
    else if (w == 1) { W = Wg; u = ug; R = 64;  Cc = 512; sh = 9; }
    else if (w == 2) { W = Wh; u = uh; R = 64;  Cc = 512; sh = 9; }
    else             { W = Wv; u = uv; R = 512; Cc = 64;  sh = 6; }

    __shared__ float us[512];
    __shared__ float vs[512];
    __shared__ float red[512];
    const int t = threadIdx.x;

    if (t < R) us[t] = ldS(u, t, f32);
    __syncthreads();

    if (t < Cc) {
        float a = 0.f;
        for (int i = 0; i < R; ++i) a += ldS(W, (long)(i << sh) + t, f32) * us[i];
        vs[t] = a;
    }
    __syncthreads();

    red[t] = (t < Cc) ? vs[t] * vs[t] : 0.f;
    __syncthreads();
    for (int s = 256; s > 0; s >>= 1) { if (t < s) red[t] += red[t + s]; __syncthreads(); }
    const float inv = 1.f / (sqrtf(red[0]) + 1e-12f);
    __syncthreads();
    if (t < Cc) vs[t] *= inv;
    __syncthreads();

    float a = 0.f;
    const int total = R * Cc;
    const int mask = Cc - 1;
    for (int idx = t; idx < total; idx += 512)
        a += us[idx >> sh] * ldS(W, idx, f32) * vs[idx & mask];
    red[t] = a;
    __syncthreads();
    for (int s = 256; s > 0; s >>= 1) { if (t < s) red[t] += red[t + s]; __syncthreads(); }
    if (t == 0) sig[w] = 1.f / red[0];
}

// ---------------------------------------------------------------------------
// projections: dst[b,c,n] = (1/sigma) * sum_k W[c,k] x[b,k,n]  (bf16 out)
// ---------------------------------------------------------------------------
__global__ __launch_bounds__(256) void proj_kernel(
    const void* __restrict__ x,
    const void* __restrict__ Wf,
    const void* __restrict__ Wg,
    const void* __restrict__ Wh,
    const int* __restrict__ dflag,
    const float* __restrict__ sig,
    unsigned short* __restrict__ fx, unsigned short* __restrict__ gx,
    unsigned short* __restrict__ hx)
{
    const int f32 = *dflag;
    const int n0 = blockIdx.x * 128;
    const int b  = blockIdx.y;
    const int w  = blockIdx.z;
    const void* __restrict__ W = (w == 0) ? Wf : ((w == 1) ? Wg : Wh);
    unsigned short* __restrict__ dst = (w == 0) ? fx : ((w == 1) ? gx : hx);
    const float scale = sig[w];

    __shared__ float Wl[64][34];
    __shared__ float xl[32][132];

    const int t  = threadIdx.x;
    const int tx = t & 15;
    const int ty = t >> 4;

    float acc[4][2][4];
    #pragma unroll
    for (int r = 0; r < 4; ++r)
        #pragma unroll
        for (int q = 0; q < 2; ++q)
            #pragma unroll
            for (int c = 0; c < 4; ++c) acc[r][q][c] = 0.f;

    for (int k0 = 0; k0 < CC; k0 += 32) {
        #pragma unroll
        for (int idx = t; idx < 1024; idx += 256) {
            int row = idx >> 4;
            int kp  = (idx & 15) * 2;
            float2 v = ld2(W, (long)row * CC + k0 + kp, f32);
            *reinterpret_cast<float2*>(&Wl[row][kp]) =
                make_float2(v.x * scale, v.y * scale);
        }
        #pragma unroll
        for (int idx = t; idx < 2048; idx += 256) {
            int kk = idx >> 6;
            int cp = (idx & 63) * 2;
            *reinterpret_cast<float2*>(&xl[kk][cp]) =
                ld2(x, (long)(b * CC + k0 + kk) * NN + n0 + cp, f32);
        }
        __syncthreads();

        #pragma unroll 8
        for (int kk = 0; kk < 32; ++kk) {
            float av[4];
            #pragma unroll
            for (int r = 0; r < 4; ++r) av[r] = Wl[ty * 4 + r][kk];
            float4 b0 = *reinterpret_cast<float4*>(&xl[kk][tx * 4]);
            float4 b1 = *reinterpret_cast<float4*>(&xl[kk][64 + tx * 4]);
            float bv0[4] = {b0.x, b0.y, b0.z, b0.w};
            float bv1[4] = {b1.x, b1.y, b1.z, b1.w};
            #pragma unroll
            for (int r = 0; r < 4; ++r)
                #pragma unroll
                for (int c = 0; c < 4; ++c) {
                    acc[r][0][c] = fmaf(av[r], bv0[c], acc[r][0][c]);
                    acc[r][1][c] = fmaf(av[r], bv1[c], acc[r][1][c]);
                }
        }
        __syncthreads();
    }

    #pragma unroll
    for (int r = 0; r < 4; ++r) {
        size_t base = (size_t)(b * CP + ty * 4 + r) * NN + n0;
        st4bf(dst + base + tx * 4, acc[r][0][0], acc[r][0][1], acc[r][0][2], acc[r][0][3]);
        st4bf(dst + base + 64 + tx * 4, acc[r][1][0], acc[r][1][1], acc[r][1][2], acc[r][1][3]);
    }
}

// ---------------------------------------------------------------------------
// pass 1: per-row (i) online max + sum of exp over all j. writes m and 1/l.
// ---------------------------------------------------------------------------
__global__ __launch_bounds__(256) void rowstats_kernel(
    const unsigned short* __restrict__ fx, const unsigned short* __restrict__ gx,
    float* __restrict__ rm, float* __restrict__ rl)
{
    const int i0 = blockIdx.x * 64;
    const int b  = blockIdx.y;
    __shared__ float fxl[64][68];
    __shared__ float gxl[64][68];
    const int t = threadIdx.x, tx = t & 15, ty = t >> 4;

    #pragma unroll
    for (int idx = t; idx < 1024; idx += 256) {
        int c = idx >> 4, i4 = (idx & 15) * 4;
        *reinterpret_cast<float4*>(&fxl[c][i4]) =
            ld4bf(fx + (size_t)(b * CP + c) * NN + i0 + i4);
    }
    float m[4], l[4];
    #pragma unroll
    for (int r = 0; r < 4; ++r) { m[r] = -1e30f; l[r] = 0.f; }
    __syncthreads();

    for (int j0 = 0; j0 < NN; j0 += 64) {
        #pragma unroll
        for (int idx = t; idx < 1024; idx += 256) {
            int c = idx >> 4, j4 = (idx & 15) * 4;
            *reinterpret_cast<float4*>(&gxl[c][j4]) =
                ld4bf(gx + (size_t)(b * CP + c) * NN + j0 + j4);
        }
        __syncthreads();

        float s[4][4];
        #pragma unroll
        for (int r = 0; r < 4; ++r)
            #pragma unroll
            for (int c = 0; c < 4; ++c) s[r][c] = 0.f;

        #pragma unroll 8
        for (int c = 0; c < 64; ++c) {
            float4 a4 = *reinterpret_cast<float4*>(&fxl[c][ty * 4]);
            float4 b4 = *reinterpret_cast<float4*>(&gxl[c][tx * 4]);
            float av[4] = {a4.x, a4.y, a4.z, a4.w};
            float bv[4] = {b4.x, b4.y, b4.z, b4.w};
            #pragma unroll
            for (int r = 0; r < 4; ++r)
                #pragma unroll
                for (int cc = 0; cc < 4; ++cc)
                    s[r][cc] = fmaf(av[r], bv[cc], s[r][cc]);
        }

        #pragma unroll
        for (int r = 0; r < 4; ++r) {
            float tm = fmaxf(fmaxf(s[r][0], s[r][1]), fmaxf(s[r][2], s[r][3]));
            tm = fmaxf(tm, __shfl_xor(tm, 1));
            tm = fmaxf(tm, __shfl_xor(tm, 2));
            tm = fmaxf(tm, __shfl_xor(tm, 4));
            tm = fmaxf(tm, __shfl_xor(tm, 8));
            float ts = __expf(s[r][0] - tm) + __expf(s[r][1] - tm) +
                       __expf(s[r][2] - tm) + __expf(s[r][3] - tm);
            ts += __shfl_xor(ts, 1);
            ts += __shfl_xor(ts, 2);
            ts += __shfl_xor(ts, 4);
            ts += __shfl_xor(ts, 8);
            float nm = fmaxf(m[r], tm);
            l[r] = l[r] * __expf(m[r] - nm) + ts * __expf(tm - nm);
            m[r] = nm;
        }
        __syncthreads();
    }

    if (tx == 0) {
        #pragma unroll
        for (int r = 0; r < 4; ++r) {
            rm[b * NN + i0 + ty * 4 + r] = m[r];
            rl[b * NN + i0 + ty * 4 + r] = 1.f / l[r];
        }
    }
}

// ---------------------------------------------------------------------------
// pass 2: op[b,c,j] = sum_i hx[b,c,i] * exp(s[i,j]-m_i) * (1/l_i)   (bf16 out)
// ---------------------------------------------------------------------------
__global__ __launch_bounds__(256) void pv_kernel(
    const unsigned short* __restrict__ fx, const unsigned short* __restrict__ gx,
    const unsigned short* __restrict__ hx,
    const float* __restrict__ rm, const float* __restrict__ rl,
    unsigned short* __restrict__ op)
{
    const int j0 = blockIdx.x * 64;
    const int b  = blockIdx.y;
    __shared__ float gxl[64][68];
    __shared__ float abuf[64][68];
    __shared__ float pl[64][68];
    const int t = threadIdx.x, tx = t & 15, ty = t >> 4;

    #pragma unroll
    for (int idx = t; idx < 1024; idx += 256) {
        int c = idx >> 4, j4 = (idx & 15) * 4;
        *reinterpret_cast<float4*>(&gxl[c][j4]) =
            ld4bf(gx + (size_t)(b * CP + c) * NN + j0 + j4);
    }
    float acc[4][4];
    #pragma unroll
    for (int r = 0; r < 4; ++r)
        #pragma unroll
        for (int c = 0; c < 4; ++c) acc[r][c] = 0.f;

    for (int i0 = 0; i0 < NN; i0 += 64) {
        #pragma unroll
        for (int idx = t; idx < 1024; idx += 256) {
            int c = idx >> 4, i4 = (idx & 15) * 4;
            *reinterpret_cast<float4*>(&abuf[c][i4]) =
                ld4bf(fx + (size_t)(b * CP + c) * NN + i0 + i4);
        }
        __syncthreads();   // (A)

        float s[4][4];
        #pragma unroll
        for (int r = 0; r < 4; ++r)
            #pragma unroll
            for (int c = 0; c < 4; ++c) s[r][c] = 0.f;
        #pragma unroll 8
        for (int c = 0; c < 64; ++c) {
            float4 a4 = *reinterpret_cast<float4*>(&abuf[c][ty * 4]);
            float4 b4 = *reinterpret_cast<float4*>(&gxl[c][tx * 4]);
            float av[4] = {a4.x, a4.y, a4.z, a4.w};
            float bv[4] = {b4.x, b4.y, b4.z, b4.w};
            #pragma unroll
            for (int r = 0; r < 4; ++r)
                #pragma unroll
                for (int cc = 0; cc < 4; ++cc)
                    s[r][cc] = fmaf(av[r], bv[cc], s[r][cc]);
        }
        #pragma unroll
        for (int r = 0; r < 4; ++r) {
            int irow = i0 + ty * 4 + r;
            float mi = rm[b * NN + irow];
            float li = rl[b * NN + irow];
            float4 p = make_float4(__expf(s[r][0] - mi) * li,
                                   __expf(s[r][1] - mi) * li,
                                   __expf(s[r][2] - mi) * li,
                                   __expf(s[r][3] - mi) * li);
            *reinterpret_cast<float4*>(&pl[ty * 4 + r][tx * 4]) = p;
        }
        __syncthreads();   // (B)

        #pragma unroll
        for (int idx = t; idx < 1024; idx += 256) {
            int c = idx >> 4, i4 = (idx & 15) * 4;
            *reinterpret_cast<float4*>(&abuf[c][i4]) =
                ld4bf(hx + (size_t)(b * CP + c) * NN + i0 + i4);
        }
        __syncthreads();   // (C)

        #pragma unroll 8
        for (int i = 0; i < 64; ++i) {
            float4 pv = *reinterpret_cast<float4*>(&pl[i][tx * 4]);
            #pragma unroll
            for (int cc = 0; cc < 4; ++cc) {
                float hv = abuf[ty * 4 + cc][i];
                acc[cc][0] = fmaf(hv, pv.x, acc[cc][0]);
                acc[cc][1] = fmaf(hv, pv.y, acc[cc][1]);
                acc[cc][2] = fmaf(hv, pv.z, acc[cc][2]);
                acc[cc][3] = fmaf(hv, pv.w, acc[cc][3]);
            }
        }
        __syncthreads();   // (D)
    }

    #pragma unroll
    for (int cc = 0; cc < 4; ++cc)
        st4bf(op + (size_t)(b * CP + ty * 4 + cc) * NN + j0 + tx * 4,
              acc[cc][0], acc[cc][1], acc[cc][2], acc[cc][3]);
}

// ---------------------------------------------------------------------------
// final: y[b,co,n] = gamma*(1/sigv)*sum_cp Wv[co,cp]*op[b,cp,n] + x[b,co,n]
// ---------------------------------------------------------------------------
__global__ __launch_bounds__(256) void outproj_kernel(
    const void* __restrict__ x,
    const void* __restrict__ Wv,
    const void* __restrict__ gamma,
    const int* __restrict__ dflag,
    const float* __restrict__ sig,
    const unsigned short* __restrict__ op,
    void* __restrict__ y)
{
    const int f32 = *dflag;
    const int n0  = blockIdx.x * 64;
    const int co0 = blockIdx.y * 64;
    const int b   = blockIdx.z;
    __shared__ float Wvl[64][68];
    __shared__ float opl[64][68];
    const int t = threadIdx.x, tx = t & 15, ty = t >> 4;
    const float scale = ldS(gamma, 0, f32) * sig[3];

    #pragma unroll
    for (int idx = t; idx < 2048; idx += 256) {
        int co = idx >> 5, cp = (idx & 31) * 2;
        float2 v = ld2(Wv, (long)(co0 + co) * CP + cp, f32);
        *reinterpret_cast<float2*>(&Wvl[co][cp]) =
            make_float2(v.x * scale, v.y * scale);
    }
    #pragma unroll
    for (int idx = t; idx < 1024; idx += 256) {
        int cp = idx >> 4, n4 = (idx & 15) * 4;
        *reinterpret_cast<float4*>(&opl[cp][n4]) =
            ld4bf(op + (size_t)(b * CP + cp) * NN + n0 + n4);
    }
    __syncthreads();

    float acc[4][4];
    #pragma unroll
    for (int r = 0; r < 4; ++r)
        #pragma unroll
        for (int c = 0; c < 4; ++c) acc[r][c] = 0.f;

    #pragma unroll 8
    for (int cp = 0; cp < 64; ++cp) {
        float av[4];
        #pragma unroll
        for (int r = 0; r < 4; ++r) av[r] = Wvl[ty * 4 + r][cp];
        float4 b4 = *reinterpret_cast<float4*>(&opl[cp][tx * 4]);
        float bv[4] = {b4.x, b4.y, b4.z, b4.w};
        #pragma unroll
        for (int r = 0; r < 4; ++r)
            #pragma unroll
            for (int c = 0; c < 4; ++c)
                acc[r][c] = fmaf(av[r], bv[c], acc[r][c]);
    }

    #pragma unroll
    for (int r = 0; r < 4; ++r) {
        size_t base = (size_t)(b * CC + co0 + ty * 4 + r) * NN + n0 + tx * 4;
        float4 xv = ld4(x, (long)base, f32);
        float o0 = acc[r][0] + xv.x, o1 = acc[r][1] + xv.y;
        float o2 = acc[r][2] + xv.z, o3 = acc[r][3] + xv.w;
        if (f32) {
            *reinterpret_cast<float4*>((float*)y + base) = make_float4(o0, o1, o2, o3);
        } else {
            uint2 o;
            o.x = pack2bf(o0, o1);
            o.y = pack2bf(o2, o3);
            *reinterpret_cast<uint2*>((unsigned short*)y + base) = o;
        }
    }
}

// ---------------------------------------------------------------------------
extern "C" void kernel_launch(void* const* d_in, const int* in_sizes, int n_in,
                              void* d_out, int out_size, void* d_ws, size_t ws_size,
                              hipStream_t stream)
{
    const void* x  = d_in[0];
    const void* Wf = d_in[1];
    const void* Wg = d_in[2];
    const void* Wh = d_in[3];
    const void* Wv = d_in[4];
    const void* uf = d_in[5];
    const void* ug = d_in[6];
    const void* uh = d_in[7];
    const void* uv = d_in[8];
    const void* gm = d_in[9];

    // ws layout (bytes), small arrays FIRST; total ~8.13 MB
    char* base = (char*)d_ws;
    int*   dfl = (int*)(base);                   // dtype flag
    float* sig = (float*)(base + 512);           // 16 B
    float* rm  = (float*)(base + 1024);          // 65,536 B
    float* rl  = (float*)(base + 1024 + 65536);  // 65,536 B
    unsigned short* fx = (unsigned short*)(base + 132096);
    unsigned short* gx = fx + (size_t)NB * CP * NN;   // +2 MB each
    unsigned short* hx = gx + (size_t)NB * CP * NN;
    unsigned short* op = hx + (size_t)NB * CP * NN;

    hipLaunchKernelGGL(detect_kernel, dim3(1), dim3(256), 0, stream,
                       (const unsigned*)x, dfl);
    hipLaunchKernelGGL(sigma_kernel, dim3(4), dim3(512), 0, stream,
                       Wf, Wg, Wh, Wv, uf, ug, uh, uv, dfl, sig);
    hipLaunchKernelGGL(proj_kernel, dim3(NN / 128, NB, 3), dim3(256), 0, stream,
                       x, Wf, Wg, Wh, dfl, sig, fx, gx, hx);
    hipLaunchKernelGGL(rowstats_kernel, dim3(NN / 64, NB), dim3(256), 0, stream,
                       fx, gx, rm, rl);
    hipLaunchKernelGGL(pv_kernel, dim3(NN / 64, NB), dim3(256), 0, stream,
                       fx, gx, hx, rm, rl, op);
    hipLaunchKernelGGL(outproj_kernel, dim3(NN / 64, CC / 64, NB), dim3(256), 0, stream,
                       x, Wv, gm, dfl, sig, op, d_out);
}

// Round 4
// 334.136 us; speedup vs baseline: 2.9380x; 2.9380x over previous
//
#include <hip/hip_runtime.h>

// SAGAN self-attention, B=4, C=512, Cp=64, N=64*64=4096. fp32 in/out
// (runtime-detected). Attention passes use bf16 MFMA (16x16x32):
//   rowstats: l_i = sum_j exp(s_ij)        (no max-subtraction; |s|<1)
//   pv:       op[c,j] = sum_i hx[c,i] * exp(s_ij)/l_i
// fx/gx stored TRANSPOSED [n][c] so S-operands are contiguous-K b128 LDS
// reads; hx natural [c][n] for the PV A-operand; P goes through LDS bf16.
// Split-K parallelism via fp32 atomics (rl, op zeroed by async memset).

#define NB 4
#define CC 512
#define CP 64
#define NN 4096
#define ISPLIT 4
#define JSPLIT 4

typedef __attribute__((ext_vector_type(8))) short short8;
typedef __attribute__((ext_vector_type(4))) float floatx4;

__device__ __forceinline__ float bf2f_u(unsigned short h) {
    return __uint_as_float((unsigned)h << 16);
}
__device__ __forceinline__ float bf16lo(unsigned v) { return __uint_as_float(v << 16); }
__device__ __forceinline__ float bf16hi(unsigned v) { return __uint_as_float(v & 0xffff0000u); }
__device__ __forceinline__ unsigned short f2bf(float f) {
    unsigned u = __float_as_uint(f);
    u += 0x7fffu + ((u >> 16) & 1u);   // RNE
    return (unsigned short)(u >> 16);
}
__device__ __forceinline__ unsigned pack2bf(float a, float b) {
    return (unsigned)f2bf(a) | ((unsigned)f2bf(b) << 16);
}
__device__ __forceinline__ float ldS(const void* p, long i, int f32) {
    return f32 ? ((const float*)p)[i] : bf2f_u(((const unsigned short*)p)[i]);
}
__device__ __forceinline__ float2 ld2(const void* p, long i, int f32) {
    if (f32) return *reinterpret_cast<const float2*>((const float*)p + i);
    unsigned v = *reinterpret_cast<const unsigned*>((const unsigned short*)p + i);
    return make_float2(bf16lo(v), bf16hi(v));
}
__device__ __forceinline__ float4 ld4(const void* p, long i, int f32) {
    if (f32) return *reinterpret_cast<const float4*>((const float*)p + i);
    uint2 v = *reinterpret_cast<const uint2*>((const unsigned short*)p + i);
    return make_float4(bf16lo(v.x), bf16hi(v.x), bf16lo(v.y), bf16hi(v.y));
}

// ---------------------------------------------------------------------------
// dtype detector: 1 if fp32, 0 if bf16.
// ---------------------------------------------------------------------------
__global__ __launch_bounds__(256) void detect_kernel(
    const unsigned* __restrict__ x, int* __restrict__ flag)
{
    __shared__ int red[256];
    const int t = threadIdx.x;
    int bad = 0;
    for (int i = t; i < 4096; i += 256) {
        unsigned w = x[i];
        float f0 = __uint_as_float(w << 16);
        float f1 = __uint_as_float(w & 0xffff0000u);
        float a0 = fabsf(f0), a1 = fabsf(f1);
        if (!(a0 <= 1e3f) || (f0 != 0.f && a0 < 1e-20f)) bad++;
        if (!(a1 <= 1e3f) || (f1 != 0.f && a1 < 1e-20f)) bad++;
    }
    red[t] = bad;
    __syncthreads();
    for (int s = 128; s > 0; s >>= 1) { if (t < s) red[t] += red[t + s]; __syncthreads(); }
    if (t == 0) *flag = (red[0] > 64) ? 1 : 0;
}

// ---------------------------------------------------------------------------
// sigma: v = normalize(W^T u); sigma = u^T (W v); writes 1/sigma.
// ---------------------------------------------------------------------------
__global__ __launch_bounds__(512) void sigma_kernel(
    const void* __restrict__ Wf, const void* __restrict__ Wg,
    const void* __restrict__ Wh, const void* __restrict__ Wv,
    const void* __restrict__ uf, const void* __restrict__ ug,
    const void* __restrict__ uh, const void* __restrict__ uv,
    const int* __restrict__ dflag, float* __restrict__ sig)
{
    const int f32 = *dflag;
    const int w = blockIdx.x;
    const void* W;
    const void* u;
    int R, Cc, sh;
    if (w == 0)      { W = Wf; u = uf; R = 64;  Cc = 512; sh = 9; }
    else if (w == 1) { W = Wg; u = ug; R = 64;  Cc = 512; sh = 9; }
    else if (w == 2) { W = Wh; u = uh; R = 64;  Cc = 512; sh = 9; }
    else             { W = Wv; u = uv; R = 512; Cc = 64;  sh = 6; }

    __shared__ float us[512];
    __shared__ float vs[512];
    __shared__ float red[512];
    const int t = threadIdx.x;

    if (t < R) us[t] = ldS(u, t, f32);
    __syncthreads();

    if (t < Cc) {
        float a = 0.f;
        for (int i = 0; i < R; ++i) a += ldS(W, (long)(i << sh) + t, f32) * us[i];
        vs[t] = a;
    }
    __syncthreads();

    red[t] = (t < Cc) ? vs[t] * vs[t] : 0.f;
    __syncthreads();
    for (int s = 256; s > 0; s >>= 1) { if (t < s) red[t] += red[t + s]; __syncthreads(); }
    const float inv = 1.f / (sqrtf(red[0]) + 1e-12f);
    __syncthreads();
    if (t < Cc) vs[t] *= inv;
    __syncthreads();

    float a = 0.f;
    const int total = R * Cc;
    const int mask = Cc - 1;
    for (int idx = t; idx < total; idx += 512)
        a += us[idx >> sh] * ldS(W, idx, f32) * vs[idx & mask];
    red[t] = a;
    __syncthreads();
    for (int s = 256; s > 0; s >>= 1) { if (t < s) red[t] += red[t + s]; __syncthreads(); }
    if (t == 0) sig[w] = 1.f / red[0];
}

// ---------------------------------------------------------------------------
// projections: (1/sigma) * W @ x. fx,gx written TRANSPOSED [b][n][c] bf16;
// hx written natural [b][c][n] bf16.
// ---------------------------------------------------------------------------
__global__ __launch_bounds__(256) void proj_kernel(
    const void* __restrict__ x,
    const void* __restrict__ Wf,
    const void* __restrict__ Wg,
    const void* __restrict__ Wh,
    const int* __restrict__ dflag,
    const float* __restrict__ sig,
    unsigned short* __restrict__ fxT, unsigned short* __restrict__ gxT,
    unsigned short* __restrict__ hx)
{
    const int f32 = *dflag;
    const int n0 = blockIdx.x * 128;
    const int b  = blockIdx.y;
    const int w  = blockIdx.z;
    const void* __restrict__ W = (w == 0) ? Wf : ((w == 1) ? Wg : Wh);
    const float scale = sig[w];

    __shared__ float Wl[64][34];
    __shared__ float xl[32][132];

    const int t  = threadIdx.x;
    const int tx = t & 15;
    const int ty = t >> 4;

    float acc[4][2][4];
    #pragma unroll
    for (int r = 0; r < 4; ++r)
        #pragma unroll
        for (int q = 0; q < 2; ++q)
            #pragma unroll
            for (int c = 0; c < 4; ++c) acc[r][q][c] = 0.f;

    for (int k0 = 0; k0 < CC; k0 += 32) {
        #pragma unroll
        for (int idx = t; idx < 1024; idx += 256) {
            int row = idx >> 4;
            int kp  = (idx & 15) * 2;
            float2 v = ld2(W, (long)row * CC + k0 + kp, f32);
            *reinterpret_cast<float2*>(&Wl[row][kp]) =
                make_float2(v.x * scale, v.y * scale);
        }
        #pragma unroll
        for (int idx = t; idx < 2048; idx += 256) {
            int kk = idx >> 6;
            int cp = (idx & 63) * 2;
            *reinterpret_cast<float2*>(&xl[kk][cp]) =
                ld2(x, (long)(b * CC + k0 + kk) * NN + n0 + cp, f32);
        }
        __syncthreads();

        #pragma unroll 8
        for (int kk = 0; kk < 32; ++kk) {
            float av[4];
            #pragma unroll
            for (int r = 0; r < 4; ++r) av[r] = Wl[ty * 4 + r][kk];
            float4 b0 = *reinterpret_cast<float4*>(&xl[kk][tx * 4]);
            float4 b1 = *reinterpret_cast<float4*>(&xl[kk][64 + tx * 4]);
            float bv0[4] = {b0.x, b0.y, b0.z, b0.w};
            float bv1[4] = {b1.x, b1.y, b1.z, b1.w};
            #pragma unroll
            for (int r = 0; r < 4; ++r)
                #pragma unroll
                for (int c = 0; c < 4; ++c) {
                    acc[r][0][c] = fmaf(av[r], bv0[c], acc[r][0][c]);
                    acc[r][1][c] = fmaf(av[r], bv1[c], acc[r][1][c]);
                }
        }
        __syncthreads();
    }

    if (w < 2) {
        unsigned short* __restrict__ dstT = (w == 0) ? fxT : gxT;
        #pragma unroll
        for (int q = 0; q < 2; ++q)
            #pragma unroll
            for (int ci = 0; ci < 4; ++ci) {
                int n = n0 + q * 64 + tx * 4 + ci;
                uint2 o;
                o.x = pack2bf(acc[0][q][ci], acc[1][q][ci]);
                o.y = pack2bf(acc[2][q][ci], acc[3][q][ci]);
                *reinterpret_cast<uint2*>(dstT + ((size_t)b * NN + n) * 64 + ty * 4) = o;
            }
    } else {
        #pragma unroll
        for (int r = 0; r < 4; ++r) {
            size_t base = (size_t)(b * CP + ty * 4 + r) * NN + n0;
            uint2 o0, o1;
            o0.x = pack2bf(acc[r][0][0], acc[r][0][1]);
            o0.y = pack2bf(acc[r][0][2], acc[r][0][3]);
            o1.x = pack2bf(acc[r][1][0], acc[r][1][1]);
            o1.y = pack2bf(acc[r][1][2], acc[r][1][3]);
            *reinterpret_cast<uint2*>(hx + base + tx * 4) = o0;
            *reinterpret_cast<uint2*>(hx + base + 64 + tx * 4) = o1;
        }
    }
}

// ---------------------------------------------------------------------------
// rowstats (MFMA): rl[b,i] += sum over this block's j-range of exp(s_ij).
// grid (NN/64, JSPLIT, NB), 256 thr. No max-subtraction (|s| < 1).
// ---------------------------------------------------------------------------
__global__ __launch_bounds__(256) void rowstats_kernel(
    const unsigned short* __restrict__ fxT, const unsigned short* __restrict__ gxT,
    float* __restrict__ rl)
{
    const int i0 = blockIdx.x * 64;
    const int jbase = blockIdx.y * (NN / JSPLIT);
    const int b = blockIdx.z;
    __shared__ unsigned short fxl[64][72];   // [i][c], 144B rows (16B aligned)
    __shared__ unsigned short gxl[64][72];   // [j][c]
    const int t = threadIdx.x;
    const int w = t >> 6, l = t & 63, l15 = l & 15, quad = l >> 4;

    {
        const uint4* src = reinterpret_cast<const uint4*>(fxT + ((size_t)b * NN + i0) * 64);
        #pragma unroll
        for (int idx = t; idx < 512; idx += 256)
            *reinterpret_cast<uint4*>(&fxl[idx >> 3][(idx & 7) * 8]) = src[idx];
    }
    float suml[4] = {0.f, 0.f, 0.f, 0.f};
    __syncthreads();

    for (int jt = 0; jt < NN / JSPLIT; jt += 64) {
        const uint4* src = reinterpret_cast<const uint4*>(gxT + ((size_t)b * NN + jbase + jt) * 64);
        #pragma unroll
        for (int idx = t; idx < 512; idx += 256)
            *reinterpret_cast<uint4*>(&gxl[idx >> 3][(idx & 7) * 8]) = src[idx];
        __syncthreads();

        short8 a0 = *reinterpret_cast<const short8*>(&fxl[w * 16 + l15][quad * 8]);
        short8 a1 = *reinterpret_cast<const short8*>(&fxl[w * 16 + l15][32 + quad * 8]);
        #pragma unroll
        for (int js = 0; js < 4; ++js) {
            short8 b0 = *reinterpret_cast<const short8*>(&gxl[js * 16 + l15][quad * 8]);
            short8 b1 = *reinterpret_cast<const short8*>(&gxl[js * 16 + l15][32 + quad * 8]);
            floatx4 s = {0.f, 0.f, 0.f, 0.f};
            s = __builtin_amdgcn_mfma_f32_16x16x32_bf16(a0, b0, s, 0, 0, 0);
            s = __builtin_amdgcn_mfma_f32_16x16x32_bf16(a1, b1, s, 0, 0, 0);
            #pragma unroll
            for (int r = 0; r < 4; ++r) suml[r] += __expf(s[r]);
        }
        __syncthreads();
    }

    #pragma unroll
    for (int r = 0; r < 4; ++r) {
        float v = suml[r];
        v += __shfl_xor(v, 1);
        v += __shfl_xor(v, 2);
        v += __shfl_xor(v, 4);
        v += __shfl_xor(v, 8);
        if (l15 == 0)
            atomicAdd(&rl[b * NN + i0 + w * 16 + quad * 4 + r], v);
    }
}

// ---------------------------------------------------------------------------
// pv (MFMA): op[b,c,j] += sum over this block's i-range of hx[c,i]*p[i,j],
// p = exp(s)/l_i. grid (NN/64, ISPLIT, NB), 256 thr, fp32 atomics into op.
// ---------------------------------------------------------------------------
__global__ __launch_bounds__(256) void pv_kernel(
    const unsigned short* __restrict__ fxT, const unsigned short* __restrict__ gxT,
    const unsigned short* __restrict__ hx, const float* __restrict__ rl,
    float* __restrict__ op)
{
    const int j0 = blockIdx.x * 64;
    const int ibase = blockIdx.y * (NN / ISPLIT);
    const int b = blockIdx.z;
    __shared__ unsigned short gxl[64][72];   // [j][c] resident
    __shared__ unsigned short fxl[64][72];   // [i][c]
    __shared__ unsigned short hxl[64][72];   // [c][i]
    __shared__ unsigned short plT[64][72];   // [j][i] bf16
    __shared__ float rli[64];
    const int t = threadIdx.x;
    const int w = t >> 6, l = t & 63, l15 = l & 15, quad = l >> 4;

    {
        const uint4* src = reinterpret_cast<const uint4*>(gxT + ((size_t)b * NN + j0) * 64);
        #pragma unroll
        for (int idx = t; idx < 512; idx += 256)
            *reinterpret_cast<uint4*>(&gxl[idx >> 3][(idx & 7) * 8]) = src[idx];
    }
    floatx4 oacc[4];
    #pragma unroll
    for (int js = 0; js < 4; ++js) oacc[js] = (floatx4){0.f, 0.f, 0.f, 0.f};

    for (int it = 0; it < NN / ISPLIT; it += 64) {
        const int i0 = ibase + it;
        {
            const uint4* srcf = reinterpret_cast<const uint4*>(fxT + ((size_t)b * NN + i0) * 64);
            #pragma unroll
            for (int idx = t; idx < 512; idx += 256)
                *reinterpret_cast<uint4*>(&fxl[idx >> 3][(idx & 7) * 8]) = srcf[idx];
            #pragma unroll
            for (int idx = t; idx < 512; idx += 256) {
                int c = idx >> 3, seg = idx & 7;
                *reinterpret_cast<uint4*>(&hxl[c][seg * 8]) =
                    *reinterpret_cast<const uint4*>(hx + (size_t)(b * CP + c) * NN + i0 + seg * 8);
            }
            if (t < 64) rli[t] = 1.f / rl[b * NN + i0 + t];
        }
        __syncthreads();   // (A) fxl/hxl/rli ready (covers gxl on first iter)

        // S = fx^T gx for this 64i x 64j tile; p -> plT (bf16, [j][i])
        short8 a0 = *reinterpret_cast<const short8*>(&fxl[w * 16 + l15][quad * 8]);
        short8 a1 = *reinterpret_cast<const short8*>(&fxl[w * 16 + l15][32 + quad * 8]);
        #pragma unroll
        for (int js = 0; js < 4; ++js) {
            short8 b0 = *reinterpret_cast<const short8*>(&gxl[js * 16 + l15][quad * 8]);
            short8 b1 = *reinterpret_cast<const short8*>(&gxl[js * 16 + l15][32 + quad * 8]);
            floatx4 s = {0.f, 0.f, 0.f, 0.f};
            s = __builtin_amdgcn_mfma_f32_16x16x32_bf16(a0, b0, s, 0, 0, 0);
            s = __builtin_amdgcn_mfma_f32_16x16x32_bf16(a1, b1, s, 0, 0, 0);
            // lane holds s for i_local = w*16 + quad*4 + r, j_local = js*16 + l15
            float p0 = __expf(s[0]) * rli[w * 16 + quad * 4 + 0];
            float p1 = __expf(s[1]) * rli[w * 16 + quad * 4 + 1];
            float p2 = __expf(s[2]) * rli[w * 16 + quad * 4 + 2];
            float p3 = __expf(s[3]) * rli[w * 16 + quad * 4 + 3];
            uint2 o;
            o.x = pack2bf(p0, p1);
            o.y = pack2bf(p2, p3);
            *reinterpret_cast<uint2*>(&plT[js * 16 + l15][w * 16 + quad * 4]) = o;
        }
        __syncthreads();   // (B) plT complete

        // PV: out[c,j] += hx[c,i] * p[i,j]
        short8 h0 = *reinterpret_cast<const short8*>(&hxl[w * 16 + l15][quad * 8]);
        short8 h1 = *reinterpret_cast<const short8*>(&hxl[w * 16 + l15][32 + quad * 8]);
        #pragma unroll
        for (int js = 0; js < 4; ++js) {
            short8 p0f = *reinterpret_cast<const short8*>(&plT[js * 16 + l15][quad * 8]);
            short8 p1f = *reinterpret_cast<const short8*>(&plT[js * 16 + l15][32 + quad * 8]);
            oacc[js] = __builtin_amdgcn_mfma_f32_16x16x32_bf16(h0, p0f, oacc[js], 0, 0, 0);
            oacc[js] = __builtin_amdgcn_mfma_f32_16x16x32_bf16(h1, p1f, oacc[js], 0, 0, 0);
        }
        __syncthreads();   // (C) reads done before next-iter staging
    }

    #pragma unroll
    for (int js = 0; js < 4; ++js)
        #pragma unroll
        for (int r = 0; r < 4; ++r) {
            int c = w * 16 + quad * 4 + r;
            int j = j0 + js * 16 + l15;
            atomicAdd(&op[(size_t)(b * CP + c) * NN + j], oacc[js][r]);
        }
}

// ---------------------------------------------------------------------------
// final: y[b,co,n] = gamma*(1/sigv)*sum_cp Wv[co,cp]*op[b,cp,n] + x[b,co,n]
// ---------------------------------------------------------------------------
__global__ __launch_bounds__(256) void outproj_kernel(
    const void* __restrict__ x,
    const void* __restrict__ Wv,
    const void* __restrict__ gamma,
    const int* __restrict__ dflag,
    const float* __restrict__ sig,
    const float* __restrict__ op,
    void* __restrict__ y)
{
    const int f32 = *dflag;
    const int n0  = blockIdx.x * 64;
    const int co0 = blockIdx.y * 64;
    const int b   = blockIdx.z;
    __shared__ float Wvl[64][68];
    __shared__ float opl[64][68];
    const int t = threadIdx.x, tx = t & 15, ty = t >> 4;
    const float scale = ldS(gamma, 0, f32) * sig[3];

    #pragma unroll
    for (int idx = t; idx < 2048; idx += 256) {
        int co = idx >> 5, cp = (idx & 31) * 2;
        float2 v = ld2(Wv, (long)(co0 + co) * CP + cp, f32);
        *reinterpret_cast<float2*>(&Wvl[co][cp]) =
            make_float2(v.x * scale, v.y * scale);
    }
    #pragma unroll
    for (int idx = t; idx < 1024; idx += 256) {
        int cp = idx >> 4, n4 = (idx & 15) * 4;
        *reinterpret_cast<float4*>(&opl[cp][n4]) =
            *reinterpret_cast<const float4*>(op + (size_t)(b * CP + cp) * NN + n0 + n4);
    }
    __syncthreads();

    float acc[4][4];
    #pragma unroll
    for (int r = 0; r < 4; ++r)
        #pragma unroll
        for (int c = 0; c < 4; ++c) acc[r][c] = 0.f;

    #pragma unroll 8
    for (int cp = 0; cp < 64; ++cp) {
        float av[4];
        #pragma unroll
        for (int r = 0; r < 4; ++r) av[r] = Wvl[ty * 4 + r][cp];
        float4 b4 = *reinterpret_cast<float4*>(&opl[cp][tx * 4]);
        float bv[4] = {b4.x, b4.y, b4.z, b4.w};
        #pragma unroll
        for (int r = 0; r < 4; ++r)
            #pragma unroll
            for (int c = 0; c < 4; ++c)
                acc[r][c] = fmaf(av[r], bv[c], acc[r][c]);
    }

    #pragma unroll
    for (int r = 0; r < 4; ++r) {
        size_t base = (size_t)(b * CC + co0 + ty * 4 + r) * NN + n0 + tx * 4;
        float4 xv = ld4(x, (long)base, f32);
        float o0 = acc[r][0] + xv.x, o1 = acc[r][1] + xv.y;
        float o2 = acc[r][2] + xv.z, o3 = acc[r][3] + xv.w;
        if (f32) {
            *reinterpret_cast<float4*>((float*)y + base) = make_float4(o0, o1, o2, o3);
        } else {
            uint2 o;
            o.x = pack2bf(o0, o1);
            o.y = pack2bf(o2, o3);
            *reinterpret_cast<uint2*>((unsigned short*)y + base) = o;
        }
    }
}

// ---------------------------------------------------------------------------
extern "C" void kernel_launch(void* const* d_in, const int* in_sizes, int n_in,
                              void* d_out, int out_size, void* d_ws, size_t ws_size,
                              hipStream_t stream)
{
    const void* x  = d_in[0];
    const void* Wf = d_in[1];
    const void* Wg = d_in[2];
    const void* Wh = d_in[3];
    const void* Wv = d_in[4];
    const void* uf = d_in[5];
    const void* ug = d_in[6];
    const void* uh = d_in[7];
    const void* uv = d_in[8];
    const void* gm = d_in[9];

    // ws layout: dfl | sig | rl (64KB) | op (4MB fp32) | fxT | gxT | hx (2MB bf16 each)
    // total ~10.3 MB
    char* base = (char*)d_ws;
    int*   dfl = (int*)(base);
    float* sig = (float*)(base + 512);
    float* rl  = (float*)(base + 1024);
    float* op  = (float*)(base + 1024 + 65536);
    unsigned short* fxT = (unsigned short*)(base + 1024 + 65536 + 4194304);
    unsigned short* gxT = fxT + (size_t)NB * CP * NN;
    unsigned short* hx  = gxT + (size_t)NB * CP * NN;

    // zero rl + op (adjacent) for the atomic accumulations
    hipMemsetAsync(rl, 0, 65536 + 4194304, stream);

    hipLaunchKernelGGL(detect_kernel, dim3(1), dim3(256), 0, stream,
                       (const unsigned*)x, dfl);
    hipLaunchKernelGGL(sigma_kernel, dim3(4), dim3(512), 0, stream,
                       Wf, Wg, Wh, Wv, uf, ug, uh, uv, dfl, sig);
    hipLaunchKernelGGL(proj_kernel, dim3(NN / 128, NB, 3), dim3(256), 0, stream,
                       x, Wf, Wg, Wh, dfl, sig, fxT, gxT, hx);
    hipLaunchKernelGGL(rowstats_kernel, dim3(NN / 64, JSPLIT, NB), dim3(256), 0, stream,
                       fxT, gxT, rl);
    hipLaunchKernelGGL(pv_kernel, dim3(NN / 64, ISPLIT, NB), dim3(256), 0, stream,
                       fxT, gxT, hx, rl, op);
    hipLaunchKernelGGL(outproj_kernel, dim3(NN / 64, CC / 64, NB), dim3(256), 0, stream,
                       x, Wv, gm, dfl, sig, op, d_out);
}

// Round 5
// 331.461 us; speedup vs baseline: 2.9617x; 1.0081x over previous
//
#include <hip/hip_runtime.h>

// SAGAN self-attention, B=4, C=512, Cp=64, N=64*64=4096. fp32 in/out
// (runtime-detected). All four GEMMs (proj f/g/h, S=QK^T, PV, outproj) on
// bf16 MFMA 16x16x32. fx/gx stored transposed [n][c]; hx natural [c][n];
// op stored transposed [n][c] fp32 (atomic split-K). No softmax max-
// subtraction (|s| small). rl/opT zeroed by async memset.

#define NB 4
#define CC 512
#define CP 64
#define NN 4096
#define ISPLIT 4
#define JSPLIT 4

typedef __attribute__((ext_vector_type(8))) short short8;
typedef __attribute__((ext_vector_type(4))) float floatx4;

__device__ __forceinline__ float bf2f_u(unsigned short h) {
    return __uint_as_float((unsigned)h << 16);
}
__device__ __forceinline__ float bf16lo(unsigned v) { return __uint_as_float(v << 16); }
__device__ __forceinline__ float bf16hi(unsigned v) { return __uint_as_float(v & 0xffff0000u); }
__device__ __forceinline__ unsigned short f2bf(float f) {
    unsigned u = __float_as_uint(f);
    u += 0x7fffu + ((u >> 16) & 1u);   // RNE
    return (unsigned short)(u >> 16);
}
__device__ __forceinline__ unsigned pack2bf(float a, float b) {
    return (unsigned)f2bf(a) | ((unsigned)f2bf(b) << 16);
}
__device__ __forceinline__ float ldS(const void* p, long i, int f32) {
    return f32 ? ((const float*)p)[i] : bf2f_u(((const unsigned short*)p)[i]);
}
__device__ __forceinline__ float2 ld2(const void* p, long i, int f32) {
    if (f32) return *reinterpret_cast<const float2*>((const float*)p + i);
    unsigned v = *reinterpret_cast<const unsigned*>((const unsigned short*)p + i);
    return make_float2(bf16lo(v), bf16hi(v));
}
__device__ __forceinline__ float4 ld4(const void* p, long i, int f32) {
    if (f32) return *reinterpret_cast<const float4*>((const float*)p + i);
    uint2 v = *reinterpret_cast<const uint2*>((const unsigned short*)p + i);
    return make_float4(bf16lo(v.x), bf16hi(v.x), bf16lo(v.y), bf16hi(v.y));
}
// 8 consecutive fp32 (or bf16) -> bf16 A/B fragment
__device__ __forceinline__ short8 frag8(const void* p, long i, int f32) {
    uint4 au;
    if (f32) {
        float4 v0 = *reinterpret_cast<const float4*>((const float*)p + i);
        float4 v1 = *reinterpret_cast<const float4*>((const float*)p + i + 4);
        au.x = pack2bf(v0.x, v0.y); au.y = pack2bf(v0.z, v0.w);
        au.z = pack2bf(v1.x, v1.y); au.w = pack2bf(v1.z, v1.w);
    } else {
        au = *reinterpret_cast<const uint4*>((const unsigned short*)p + i);
    }
    return *reinterpret_cast<short8*>(&au);
}

// ---------------------------------------------------------------------------
// dtype detector: 1 if fp32, 0 if bf16.
// ---------------------------------------------------------------------------
__global__ __launch_bounds__(256) void detect_kernel(
    const unsigned* __restrict__ x, int* __restrict__ flag)
{
    __shared__ int red[256];
    const int t = threadIdx.x;
    int bad = 0;
    for (int i = t; i < 4096; i += 256) {
        unsigned w = x[i];
        float f0 = __uint_as_float(w << 16);
        float f1 = __uint_as_float(w & 0xffff0000u);
        float a0 = fabsf(f0), a1 = fabsf(f1);
        if (!(a0 <= 1e3f) || (f0 != 0.f && a0 < 1e-20f)) bad++;
        if (!(a1 <= 1e3f) || (f1 != 0.f && a1 < 1e-20f)) bad++;
    }
    red[t] = bad;
    __syncthreads();
    for (int s = 128; s > 0; s >>= 1) { if (t < s) red[t] += red[t + s]; __syncthreads(); }
    if (t == 0) *flag = (red[0] > 64) ? 1 : 0;
}

// ---------------------------------------------------------------------------
// sigma: v = normalize(W^T u); sigma = u^T (W v); writes 1/sigma.
// ---------------------------------------------------------------------------
__global__ __launch_bounds__(512) void sigma_kernel(
    const void* __restrict__ Wf, const void* __restrict__ Wg,
    const void* __restrict__ Wh, const void* __restrict__ Wv,
    const void* __restrict__ uf, const void* __restrict__ ug,
    const void* __restrict__ uh, const void* __restrict__ uv,
    const int* __restrict__ dflag, float* __restrict__ sig)
{
    const int f32 = *dflag;
    const int w = blockIdx.x;
    const void* W;
    const void* u;
    int R, Cc, sh;
    if (w == 0)      { W = Wf; u = uf; R = 64;  Cc = 512; sh = 9; }
    else if (w == 1) { W = Wg; u = ug; R = 64;  Cc = 512; sh = 9; }
    else if (w == 2) { W = Wh; u = uh; R = 64;  Cc = 512; sh = 9; }
    else             { W = Wv; u = uv; R = 512; Cc = 64;  sh = 6; }

    __shared__ float us[512];
    __shared__ float vs[512];
    __shared__ float red[512];
    const int t = threadIdx.x;

    if (t < R) us[t] = ldS(u, t, f32);
    __syncthreads();

    if (t < Cc) {
        float a = 0.f;
        for (int i = 0; i < R; ++i) a += ldS(W, (long)(i << sh) + t, f32) * us[i];
        vs[t] = a;
    }
    __syncthreads();

    red[t] = (t < Cc) ? vs[t] * vs[t] : 0.f;
    __syncthreads();
    for (int s = 256; s > 0; s >>= 1) { if (t < s) red[t] += red[t + s]; __syncthreads(); }
    const float inv = 1.f / (sqrtf(red[0]) + 1e-12f);
    __syncthreads();
    if (t < Cc) vs[t] *= inv;
    __syncthreads();

    float a = 0.f;
    const int total = R * Cc;
    const int mask = Cc - 1;
    for (int idx = t; idx < total; idx += 512)
        a += us[idx >> sh] * ldS(W, idx, f32) * vs[idx & mask];
    red[t] = a;
    __syncthreads();
    for (int s = 256; s > 0; s >>= 1) { if (t < s) red[t] += red[t + s]; __syncthreads(); }
    if (t == 0) sig[w] = 1.f / red[0];
}

// ---------------------------------------------------------------------------
// proj (MFMA): out^T[n][c] = sum_k x^T[n][k] * (W/sigma)^T[k][c].
// A-frags (x columns) loaded straight from global (fp32->bf16, coalesces to
// 4x64B lines/instr); W chunk staged scaled+bf16 in LDS (rows contiguous-k).
// grid (NN/64, NB, 3weights), 256 thr. wi<2 -> write dstT [n][c]; wi=2 -> hx [c][n].
// ---------------------------------------------------------------------------
__global__ __launch_bounds__(256) void proj_kernel(
    const void* __restrict__ x,
    const void* __restrict__ Wf,
    const void* __restrict__ Wg,
    const void* __restrict__ Wh,
    const int* __restrict__ dflag,
    const float* __restrict__ sig,
    unsigned short* __restrict__ fxT, unsigned short* __restrict__ gxT,
    unsigned short* __restrict__ hx)
{
    const int f32 = *dflag;
    const int n0 = blockIdx.x * 64;
    const int b  = blockIdx.y;
    const int wi = blockIdx.z;
    const void* __restrict__ W = (wi == 0) ? Wf : ((wi == 1) ? Wg : Wh);
    const float scale = sig[wi];

    __shared__ unsigned short Wl[64][72];   // [c][kk], 144B rows

    const int t = threadIdx.x;
    const int wv = t >> 6, l = t & 63, l15 = l & 15, quad = l >> 4;
    const int n = n0 + 16 * wv + l15;       // this lane's A row (n index)

    floatx4 acc[4];
    #pragma unroll
    for (int ct = 0; ct < 4; ++ct) acc[ct] = (floatx4){0.f, 0.f, 0.f, 0.f};

    for (int kc = 0; kc < CC; kc += 64) {
        // stage W chunk (64c x 64k) scaled -> bf16
        #pragma unroll
        for (int idx = t; idx < 2048; idx += 256) {
            int c  = idx >> 5;
            int kk = (idx & 31) * 2;
            float2 v = ld2(W, (long)c * CC + kc + kk, f32);
            *reinterpret_cast<unsigned*>(&Wl[c][kk]) = pack2bf(v.x * scale, v.y * scale);
        }
        __syncthreads();

        #pragma unroll
        for (int ks = 0; ks < 2; ++ks) {
            const int kbase = kc + ks * 32 + quad * 8;
            float xv[8];
            #pragma unroll
            for (int j = 0; j < 8; ++j)
                xv[j] = ldS(x, ((long)b * CC + kbase + j) * NN + n, f32);
            uint4 au;
            au.x = pack2bf(xv[0], xv[1]); au.y = pack2bf(xv[2], xv[3]);
            au.z = pack2bf(xv[4], xv[5]); au.w = pack2bf(xv[6], xv[7]);
            short8 a = *reinterpret_cast<short8*>(&au);
            #pragma unroll
            for (int ct = 0; ct < 4; ++ct) {
                short8 bfr = *reinterpret_cast<const short8*>(
                    &Wl[ct * 16 + l15][ks * 32 + quad * 8]);
                acc[ct] = __builtin_amdgcn_mfma_f32_16x16x32_bf16(a, bfr, acc[ct], 0, 0, 0);
            }
        }
        __syncthreads();
    }

    // D: row = quad*4+r (n-local), col = l15 (c-local within ct tile)
    if (wi < 2) {
        unsigned short* __restrict__ dstT = (wi == 0) ? fxT : gxT;
        #pragma unroll
        for (int ct = 0; ct < 4; ++ct)
            #pragma unroll
            for (int r = 0; r < 4; ++r)
                dstT[((size_t)b * NN + n0 + 16 * wv + quad * 4 + r) * 64 + ct * 16 + l15] =
                    f2bf(acc[ct][r]);
    } else {
        #pragma unroll
        for (int ct = 0; ct < 4; ++ct) {
            uint2 o;
            o.x = pack2bf(acc[ct][0], acc[ct][1]);
            o.y = pack2bf(acc[ct][2], acc[ct][3]);
            *reinterpret_cast<uint2*>(
                &hx[((size_t)b * CP + ct * 16 + l15) * NN + n0 + 16 * wv + quad * 4]) = o;
        }
    }
}

// ---------------------------------------------------------------------------
// rowstats (MFMA): rl[b,i] += sum_j exp(s_ij) over this block's j-range.
// ---------------------------------------------------------------------------
__global__ __launch_bounds__(256) void rowstats_kernel(
    const unsigned short* __restrict__ fxT, const unsigned short* __restrict__ gxT,
    float* __restrict__ rl)
{
    const int i0 = blockIdx.x * 64;
    const int jbase = blockIdx.y * (NN / JSPLIT);
    const int b = blockIdx.z;
    __shared__ unsigned short fxl[64][72];
    __shared__ unsigned short gxl[64][72];
    const int t = threadIdx.x;
    const int w = t >> 6, l = t & 63, l15 = l & 15, quad = l >> 4;

    {
        const uint4* src = reinterpret_cast<const uint4*>(fxT + ((size_t)b * NN + i0) * 64);
        #pragma unroll
        for (int idx = t; idx < 512; idx += 256)
            *reinterpret_cast<uint4*>(&fxl[idx >> 3][(idx & 7) * 8]) = src[idx];
    }
    float suml[4] = {0.f, 0.f, 0.f, 0.f};
    __syncthreads();

    for (int jt = 0; jt < NN / JSPLIT; jt += 64) {
        const uint4* src = reinterpret_cast<const uint4*>(gxT + ((size_t)b * NN + jbase + jt) * 64);
        #pragma unroll
        for (int idx = t; idx < 512; idx += 256)
            *reinterpret_cast<uint4*>(&gxl[idx >> 3][(idx & 7) * 8]) = src[idx];
        __syncthreads();

        short8 a0 = *reinterpret_cast<const short8*>(&fxl[w * 16 + l15][quad * 8]);
        short8 a1 = *reinterpret_cast<const short8*>(&fxl[w * 16 + l15][32 + quad * 8]);
        #pragma unroll
        for (int js = 0; js < 4; ++js) {
            short8 b0 = *reinterpret_cast<const short8*>(&gxl[js * 16 + l15][quad * 8]);
            short8 b1 = *reinterpret_cast<const short8*>(&gxl[js * 16 + l15][32 + quad * 8]);
            floatx4 s = {0.f, 0.f, 0.f, 0.f};
            s = __builtin_amdgcn_mfma_f32_16x16x32_bf16(a0, b0, s, 0, 0, 0);
            s = __builtin_amdgcn_mfma_f32_16x16x32_bf16(a1, b1, s, 0, 0, 0);
            #pragma unroll
            for (int r = 0; r < 4; ++r) suml[r] += __expf(s[r]);
        }
        __syncthreads();
    }

    #pragma unroll
    for (int r = 0; r < 4; ++r) {
        float v = suml[r];
        v += __shfl_xor(v, 1);
        v += __shfl_xor(v, 2);
        v += __shfl_xor(v, 4);
        v += __shfl_xor(v, 8);
        if (l15 == 0)
            atomicAdd(&rl[b * NN + i0 + w * 16 + quad * 4 + r], v);
    }
}

// ---------------------------------------------------------------------------
// pv (MFMA): opT[b,j,c] += sum_i hx[c,i] * exp(s_ij)/l_i over i-range.
// ---------------------------------------------------------------------------
__global__ __launch_bounds__(256) void pv_kernel(
    const unsigned short* __restrict__ fxT, const unsigned short* __restrict__ gxT,
    const unsigned short* __restrict__ hx, const float* __restrict__ rl,
    float* __restrict__ opT)
{
    const int j0 = blockIdx.x * 64;
    const int ibase = blockIdx.y * (NN / ISPLIT);
    const int b = blockIdx.z;
    __shared__ unsigned short gxl[64][72];
    __shared__ unsigned short fxl[64][72];
    __shared__ unsigned short hxl[64][72];
    __shared__ unsigned short plT[64][72];
    __shared__ float rli[64];
    const int t = threadIdx.x;
    const int w = t >> 6, l = t & 63, l15 = l & 15, quad = l >> 4;

    {
        const uint4* src = reinterpret_cast<const uint4*>(gxT + ((size_t)b * NN + j0) * 64);
        #pragma unroll
        for (int idx = t; idx < 512; idx += 256)
            *reinterpret_cast<uint4*>(&gxl[idx >> 3][(idx & 7) * 8]) = src[idx];
    }
    floatx4 oacc[4];
    #pragma unroll
    for (int js = 0; js < 4; ++js) oacc[js] = (floatx4){0.f, 0.f, 0.f, 0.f};

    for (int it = 0; it < NN / ISPLIT; it += 64) {
        const int i0 = ibase + it;
        {
            const uint4* srcf = reinterpret_cast<const uint4*>(fxT + ((size_t)b * NN + i0) * 64);
            #pragma unroll
            for (int idx = t; idx < 512; idx += 256)
                *reinterpret_cast<uint4*>(&fxl[idx >> 3][(idx & 7) * 8]) = srcf[idx];
            #pragma unroll
            for (int idx = t; idx < 512; idx += 256) {
                int c = idx >> 3, seg = idx & 7;
                *reinterpret_cast<uint4*>(&hxl[c][seg * 8]) =
                    *reinterpret_cast<const uint4*>(hx + (size_t)(b * CP + c) * NN + i0 + seg * 8);
            }
            if (t < 64) rli[t] = 1.f / rl[b * NN + i0 + t];
        }
        __syncthreads();   // (A)

        short8 a0 = *reinterpret_cast<const short8*>(&fxl[w * 16 + l15][quad * 8]);
        short8 a1 = *reinterpret_cast<const short8*>(&fxl[w * 16 + l15][32 + quad * 8]);
        #pragma unroll
        for (int js = 0; js < 4; ++js) {
            short8 b0 = *reinterpret_cast<const short8*>(&gxl[js * 16 + l15][quad * 8]);
            short8 b1 = *reinterpret_cast<const short8*>(&gxl[js * 16 + l15][32 + quad * 8]);
            floatx4 s = {0.f, 0.f, 0.f, 0.f};
            s = __builtin_amdgcn_mfma_f32_16x16x32_bf16(a0, b0, s, 0, 0, 0);
            s = __builtin_amdgcn_mfma_f32_16x16x32_bf16(a1, b1, s, 0, 0, 0);
            float p0 = __expf(s[0]) * rli[w * 16 + quad * 4 + 0];
            float p1 = __expf(s[1]) * rli[w * 16 + quad * 4 + 1];
            float p2 = __expf(s[2]) * rli[w * 16 + quad * 4 + 2];
            float p3 = __expf(s[3]) * rli[w * 16 + quad * 4 + 3];
            uint2 o;
            o.x = pack2bf(p0, p1);
            o.y = pack2bf(p2, p3);
            *reinterpret_cast<uint2*>(&plT[js * 16 + l15][w * 16 + quad * 4]) = o;
        }
        __syncthreads();   // (B)

        short8 h0 = *reinterpret_cast<const short8*>(&hxl[w * 16 + l15][quad * 8]);
        short8 h1 = *reinterpret_cast<const short8*>(&hxl[w * 16 + l15][32 + quad * 8]);
        #pragma unroll
        for (int js = 0; js < 4; ++js) {
            short8 p0f = *reinterpret_cast<const short8*>(&plT[js * 16 + l15][quad * 8]);
            short8 p1f = *reinterpret_cast<const short8*>(&plT[js * 16 + l15][32 + quad * 8]);
            oacc[js] = __builtin_amdgcn_mfma_f32_16x16x32_bf16(h0, p0f, oacc[js], 0, 0, 0);
            oacc[js] = __builtin_amdgcn_mfma_f32_16x16x32_bf16(h1, p1f, oacc[js], 0, 0, 0);
        }
        __syncthreads();   // (C)
    }

    #pragma unroll
    for (int js = 0; js < 4; ++js)
        #pragma unroll
        for (int r = 0; r < 4; ++r) {
            int c = w * 16 + quad * 4 + r;
            int j = j0 + js * 16 + l15;
            atomicAdd(&opT[((size_t)b * NN + j) * CP + c], oacc[js][r]);
        }
}

// ---------------------------------------------------------------------------
// outproj (MFMA): y^T[n][co] = scale * sum_cp opT[n][cp] Wv^T[cp][co] + x.
// A-frags from global opT (fp32->bf16); B-frags from global Wv.
// grid (NN/64, CC/128, NB); wave covers 32 co; scale applied at epilogue.
// ---------------------------------------------------------------------------
__global__ __launch_bounds__(256) void outproj_kernel(
    const void* __restrict__ x,
    const void* __restrict__ Wv,
    const void* __restrict__ gamma,
    const int* __restrict__ dflag,
    const float* __restrict__ sig,
    const float* __restrict__ opT,
    void* __restrict__ y)
{
    const int f32 = *dflag;
    const int n0     = blockIdx.x * 64;
    const int cobase = blockIdx.y * 128;
    const int b      = blockIdx.z;
    const int t = threadIdx.x;
    const int wv = t >> 6, l = t & 63, l15 = l & 15, quad = l >> 4;
    const float scale = ldS(gamma, 0, f32) * sig[3];

    floatx4 acc[4][2];
    #pragma unroll
    for (int ns = 0; ns < 4; ++ns)
        #pragma unroll
        for (int ct = 0; ct < 2; ++ct) acc[ns][ct] = (floatx4){0.f, 0.f, 0.f, 0.f};

    #pragma unroll
    for (int ks = 0; ks < 2; ++ks) {
        const int kb = ks * 32 + quad * 8;
        short8 a[4];
        #pragma unroll
        for (int ns = 0; ns < 4; ++ns)
            a[ns] = frag8(opT, ((long)b * NN + n0 + 16 * ns + l15) * CP + kb, 1);
        #pragma unroll
        for (int ct = 0; ct < 2; ++ct) {
            const int co = cobase + 32 * wv + 16 * ct + l15;
            short8 bfr = frag8(Wv, (long)co * CP + kb, f32);
            #pragma unroll
            for (int ns = 0; ns < 4; ++ns)
                acc[ns][ct] = __builtin_amdgcn_mfma_f32_16x16x32_bf16(a[ns], bfr, acc[ns][ct], 0, 0, 0);
        }
    }

    // D: row = quad*4+r (n-local), col = l15 -> co
    #pragma unroll
    for (int ns = 0; ns < 4; ++ns)
        #pragma unroll
        for (int ct = 0; ct < 2; ++ct) {
            const int co = cobase + 32 * wv + 16 * ct + l15;
            const long base = ((long)b * CC + co) * NN + n0 + 16 * ns + quad * 4;
            float4 xv = ld4(x, base, f32);
            float o0 = fmaf(scale, acc[ns][ct][0], xv.x);
            float o1 = fmaf(scale, acc[ns][ct][1], xv.y);
            float o2 = fmaf(scale, acc[ns][ct][2], xv.z);
            float o3 = fmaf(scale, acc[ns][ct][3], xv.w);
            if (f32) {
                *reinterpret_cast<float4*>((float*)y + base) = make_float4(o0, o1, o2, o3);
            } else {
                uint2 o;
                o.x = pack2bf(o0, o1);
                o.y = pack2bf(o2, o3);
                *reinterpret_cast<uint2*>((unsigned short*)y + base) = o;
            }
        }
}

// ---------------------------------------------------------------------------
extern "C" void kernel_launch(void* const* d_in, const int* in_sizes, int n_in,
                              void* d_out, int out_size, void* d_ws, size_t ws_size,
                              hipStream_t stream)
{
    const void* x  = d_in[0];
    const void* Wf = d_in[1];
    const void* Wg = d_in[2];
    const void* Wh = d_in[3];
    const void* Wv = d_in[4];
    const void* uf = d_in[5];
    const void* ug = d_in[6];
    const void* uh = d_in[7];
    const void* uv = d_in[8];
    const void* gm = d_in[9];

    // ws: dfl | sig | rl (64KB) | opT (4MB fp32) | fxT | gxT | hx (2MB bf16 each)
    char* base = (char*)d_ws;
    int*   dfl = (int*)(base);
    float* sig = (float*)(base + 512);
    float* rl  = (float*)(base + 1024);
    float* opT = (float*)(base + 1024 + 65536);
    unsigned short* fxT = (unsigned short*)(base + 1024 + 65536 + 4194304);
    unsigned short* gxT = fxT + (size_t)NB * CP * NN;
    unsigned short* hx  = gxT + (size_t)NB * CP * NN;

    hipMemsetAsync(rl, 0, 65536 + 4194304, stream);

    hipLaunchKernelGGL(detect_kernel, dim3(1), dim3(256), 0, stream,
                       (const unsigned*)x, dfl);
    hipLaunchKernelGGL(sigma_kernel, dim3(4), dim3(512), 0, stream,
                       Wf, Wg, Wh, Wv, uf, ug, uh, uv, dfl, sig);
    hipLaunchKernelGGL(proj_kernel, dim3(NN / 64, NB, 3), dim3(256), 0, stream,
                       x, Wf, Wg, Wh, dfl, sig, fxT, gxT, hx);
    hipLaunchKernelGGL(rowstats_kernel, dim3(NN / 64, JSPLIT, NB), dim3(256), 0, stream,
                       fxT, gxT, rl);
    hipLaunchKernelGGL(pv_kernel, dim3(NN / 64, ISPLIT, NB), dim3(256), 0, stream,
                       fxT, gxT, hx, rl, opT);
    hipLaunchKernelGGL(outproj_kernel, dim3(NN / 64, CC / 128, NB), dim3(256), 0, stream,
                       x, Wv, gm, dfl, sig, opT, d_out);
}